// Round 1
// baseline (252.475 us; speedup 1.0000x reference)
//
#include <hip/hip_runtime.h>

// All tensors FLOAT32 (proven R5). GEMMs: bf16 MFMA (err 0.031 < 0.108 thr).
// Interp (this round): O(Nt*Ns) ranking moved to MFMA. Keys = |s|^2 - 2 t.s
// via hi/lo bf16 split packed along K of mfma_f32_16x16x32_bf16 (fragment
// layouts identical to the proven gemm_a scheme). Key error eps <= 0.30;
// phase-2 margin 1.0 >= 2*eps guarantees candidate set contains exact top-3.
// Final selection recomputes exact rn d2 ((dx2+dy2)+dz2, no FMA) over the
// ~3.3 candidates/target in ascending-j order with strict-< insertion ==
// lax.top_k stable tie-break -> selection + weights bit-identical to the
// previous passing brute-force kernel.

typedef __attribute__((ext_vector_type(8))) short bf16x8;
typedef __attribute__((ext_vector_type(4))) float f32x4;

__device__ __forceinline__ unsigned short f2bf(float f) {
    union { float f; unsigned u; } v; v.f = f;
    return (unsigned short)((v.u + 0x7fffu + ((v.u >> 16) & 1u)) >> 16); // RNE
}
__device__ __forceinline__ float bf2f(unsigned short u) {
    union { unsigned u; float f; } v; v.u = (unsigned)u << 16; return v.f;
}
__device__ __forceinline__ unsigned pack2(float a, float b) {
    return (unsigned)f2bf(a) | ((unsigned)f2bf(b) << 16);
}

// B-side key fragment for source s (shifted by -32):
// lo = K slots 0-7  = [qh, ql, shx, shy, shz, slx, sly, slz]
// hi = K slots 8-15 = [shx, shy, shz, slx, sly, slz, 0, 0]
__device__ __forceinline__ void bfrag_store(float x, float y, float z,
                                            uint4* lo, uint4* hi) {
    float sx = x - 32.f, sy = y - 32.f, sz = z - 32.f;
    unsigned short hx = f2bf(sx), hy = f2bf(sy), hz = f2bf(sz);
    unsigned short lx = f2bf(sx - bf2f(hx));
    unsigned short ly = f2bf(sy - bf2f(hy));
    unsigned short lz = f2bf(sz - bf2f(hz));
    float q = __fadd_rn(__fadd_rn(__fmul_rn(sx, sx), __fmul_rn(sy, sy)),
                        __fmul_rn(sz, sz));
    unsigned short qh = f2bf(q);
    unsigned short ql = f2bf(q - bf2f(qh));
    uint4 L, H;
    L.x = (unsigned)qh | ((unsigned)ql << 16);
    L.y = (unsigned)hx | ((unsigned)hy << 16);
    L.z = (unsigned)hz | ((unsigned)lx << 16);
    L.w = (unsigned)ly | ((unsigned)lz << 16);
    H.x = (unsigned)hx | ((unsigned)hy << 16);
    H.y = (unsigned)hz | ((unsigned)lx << 16);
    H.z = (unsigned)ly | ((unsigned)lz << 16);
    H.w = 0u;
    *lo = L; *hi = H;
}

// ---------- prep: xyz -> padded float4, key fragments, zero BN stats ----------
__global__ __launch_bounds__(256)
void prep_kernel(const float* __restrict__ p1, const float* __restrict__ p2,
                 const float* __restrict__ p4,
                 float4* __restrict__ x1, float4* __restrict__ x2, float4* __restrict__ x4,
                 uint4* __restrict__ bf2lo, uint4* __restrict__ bf2hi,
                 uint4* __restrict__ bf4lo, uint4* __restrict__ bf4hi,
                 float* __restrict__ st1, float* __restrict__ st2) {
    int i = blockIdx.x * 256 + threadIdx.x;
    if (i < 256) { st1[i] = 0.f; st2[i] = 0.f; }
    const int P1 = 16384, P2 = 8192, P4 = 4096;
    if (i < P1) {
        x1[i] = make_float4(p1[i*3], p1[i*3+1], p1[i*3+2], 0.f);
    } else if (i < P1 + P2) {
        int j = i - P1;
        float x = p2[j*3], y = p2[j*3+1], z = p2[j*3+2];
        x2[j] = make_float4(x, y, z, 0.f);
        bfrag_store(x, y, z, &bf2lo[j], &bf2hi[j]);
    } else if (i < P1 + P2 + P4) {
        int j = i - P1 - P2;
        float x = p4[j*3], y = p4[j*3+1], z = p4[j*3+2];
        x4[j] = make_float4(x, y, z, 0.f);
        bfrag_store(x, y, z, &bf4lo[j], &bf4hi[j]);
    }
}

// ---------- 3-NN interpolate via MFMA keys ----------
// Block: 256 thr = 4 waves = 2 target-groups(16 tgt) x 2 source-slices.
// Per wave: keys for 16 tgt x (Ns/2) src via 16x16x32 bf16 MFMA tiles.
#define KMARGIN 1.0f
#define CAP 16

__global__ __launch_bounds__(256)
void nn_interp_mfma(const float4* __restrict__ tgt, int Nt,
                    const float4* __restrict__ src, int Ns,
                    const uint4* __restrict__ bfLo, const uint4* __restrict__ bfHi,
                    const float* __restrict__ feats, float* __restrict__ out) {
    __shared__ float smrg[4][16][3];
    __shared__ float kthr[32];
    __shared__ int   scnt[32];
    __shared__ int   scand[32][CAP];
    __shared__ float swv[32][3];
    __shared__ int   sgv[32][3];

    const int tid = threadIdx.x;
    const int lane = tid & 63, w = tid >> 6;
    const int col16 = lane & 15, quad = lane >> 4;
    const int bb = blockIdx.y;
    const int tb = blockIdx.x * 32;
    const int g = w >> 1, slice = w & 1;
    const int ntile = Ns >> 5;              // 16-src tiles in this wave's half
    const int sbase = slice * (Ns >> 1);

    // ---- A fragment (constant): row = lane&15, k = quad*8 + i.
    // quad0 k0-7: [1, 1, -2thx, -2thy, -2thz, -2thx, -2thy, -2thz]
    // quad1 k8-15:[-2tlx,-2tly,-2tlz,-2tlx,-2tly,-2tlz, 0, 0]
    // quads 2-3: zero A => k16-31 contribute 0 regardless of B (finite bf16).
    float4 tw = tgt[bb * Nt + tb + g * 16 + col16];
    bf16x8 afrag;
    {
        float cx = tw.x - 32.f, cy = tw.y - 32.f, cz = tw.z - 32.f;
        unsigned short hx = f2bf(cx), hy = f2bf(cy), hz = f2bf(cz);
        short mhx = (short)f2bf(-2.f * bf2f(hx));
        short mhy = (short)f2bf(-2.f * bf2f(hy));
        short mhz = (short)f2bf(-2.f * bf2f(hz));
        short mlx = (short)f2bf(-2.f * (cx - bf2f(hx)));
        short mly = (short)f2bf(-2.f * (cy - bf2f(hy)));
        short mlz = (short)f2bf(-2.f * (cz - bf2f(hz)));
        const short ONE = (short)0x3F80;
        #pragma unroll
        for (int i = 0; i < 8; ++i) afrag[i] = 0;
        if (quad == 0) {
            afrag[0] = ONE; afrag[1] = ONE;
            afrag[2] = mhx; afrag[3] = mhy; afrag[4] = mhz;
            afrag[5] = mhx; afrag[6] = mhy; afrag[7] = mhz;
        } else if (quad == 1) {
            afrag[0] = mlx; afrag[1] = mly; afrag[2] = mlz;
            afrag[3] = mlx; afrag[4] = mly; afrag[5] = mlz;
        }
    }

    // B ptr: quads 0,2 -> lo, quads 1,3 -> hi (2-3 loads are harmless dupes;
    // their A is zero, output lanes still hold valid keys for rows 8-15).
    const uint4* bp = ((quad & 1) ? bfHi : bfLo) + (size_t)bb * Ns + sbase + col16;
    const f32x4 z4 = {0.f, 0.f, 0.f, 0.f};

    // ---- phase 1: value-only top-3 keys per (lane, row-reg) ----
    float r0[4], r1[4], r2[4];
    #pragma unroll
    for (int i = 0; i < 4; ++i) { r0[i] = 3.4e38f; r1[i] = 3.4e38f; r2[i] = 3.4e38f; }

    #pragma unroll 2
    for (int t = 0; t < ntile; ++t) {
        bf16x8 bfrag = *(const bf16x8*)(bp + (size_t)t * 16);
        f32x4 acc = __builtin_amdgcn_mfma_f32_16x16x32_bf16(afrag, bfrag, z4, 0, 0, 0);
        #pragma unroll
        for (int i = 0; i < 4; ++i) {
            float kk = acc[i];
            float n0 = fminf(r0[i], kk);
            float n1 = __builtin_amdgcn_fmed3f(r0[i], r1[i], kk);
            float n2 = fminf(r2[i], fmaxf(r1[i], kk));
            r0[i] = n0; r1[i] = n1; r2[i] = n2;
        }
    }

    // ---- merge sorted triples across the 16 lanes of each quad group ----
    #pragma unroll
    for (int m = 1; m <= 8; m <<= 1) {
        #pragma unroll
        for (int i = 0; i < 4; ++i) {
            float b0 = __shfl_xor(r0[i], m);
            float b1 = __shfl_xor(r1[i], m);
            float b2 = __shfl_xor(r2[i], m);
            float n0 = fminf(r0[i], b0);
            float n1 = fminf(fminf(r1[i], b1), fmaxf(r0[i], b0));
            float n2 = fminf(fminf(r2[i], b2),
                             fminf(fmaxf(r1[i], b0), fmaxf(r0[i], b1)));
            r0[i] = n0; r1[i] = n1; r2[i] = n2;
        }
    }
    if (col16 == 0) {
        #pragma unroll
        for (int i = 0; i < 4; ++i) {
            smrg[w][quad * 4 + i][0] = r0[i];
            smrg[w][quad * 4 + i][1] = r1[i];
            smrg[w][quad * 4 + i][2] = r2[i];
        }
    }
    __syncthreads();

    // ---- K3 per target (merge the 2 source-slice waves), set threshold ----
    if (tid < 32) {
        int gg = tid >> 4, r16 = tid & 15;
        float m0 = 3.4e38f, m1 = 3.4e38f, m2 = 3.4e38f;
        #pragma unroll
        for (int ww = 0; ww < 2; ++ww)
            #pragma unroll
            for (int k = 0; k < 3; ++k) {
                float d = smrg[gg * 2 + ww][r16][k];
                float n0 = fminf(m0, d);
                float n1 = __builtin_amdgcn_fmed3f(m0, m1, d);
                float n2 = fminf(m2, fmaxf(m1, d));
                m0 = n0; m1 = n1; m2 = n2;
            }
        kthr[tid] = m2 + KMARGIN;      // margin >= 2*eps (eps<=0.30)
        scnt[tid] = 0;
    }
    __syncthreads();

    // ---- phase 2: rescan (bit-identical keys), extract candidates ----
    float t0 = kthr[g * 16 + quad * 4 + 0];
    float t1 = kthr[g * 16 + quad * 4 + 1];
    float t2 = kthr[g * 16 + quad * 4 + 2];
    float t3 = kthr[g * 16 + quad * 4 + 3];

    #pragma unroll 2
    for (int t = 0; t < ntile; ++t) {
        bf16x8 bfrag = *(const bf16x8*)(bp + (size_t)t * 16);
        f32x4 acc = __builtin_amdgcn_mfma_f32_16x16x32_bf16(afrag, bfrag, z4, 0, 0, 0);
        unsigned long long h = __ballot(acc[0] <= t0) | __ballot(acc[1] <= t1)
                             | __ballot(acc[2] <= t2) | __ballot(acc[3] <= t3);
        if (h) {
            int j = sbase + t * 16 + col16;
            if (acc[0] <= t0) { int p = atomicAdd(&scnt[g*16+quad*4+0], 1); if (p < CAP) scand[g*16+quad*4+0][p] = j; }
            if (acc[1] <= t1) { int p = atomicAdd(&scnt[g*16+quad*4+1], 1); if (p < CAP) scand[g*16+quad*4+1][p] = j; }
            if (acc[2] <= t2) { int p = atomicAdd(&scnt[g*16+quad*4+2], 1); if (p < CAP) scand[g*16+quad*4+2][p] = j; }
            if (acc[3] <= t3) { int p = atomicAdd(&scnt[g*16+quad*4+3], 1); if (p < CAP) scand[g*16+quad*4+3][p] = j; }
        }
    }
    __syncthreads();

    // ---- exact final selection (bit-identical to brute force) ----
    if (tid < 32) {
        int n = min(scnt[tid], CAP);
        for (int a = 0; a < n - 1; ++a) {          // sort candidates by j asc
            int best = a;
            for (int c = a + 1; c < n; ++c)
                if (scand[tid][c] < scand[tid][best]) best = c;
            int tmp = scand[tid][a]; scand[tid][a] = scand[tid][best]; scand[tid][best] = tmp;
        }
        float4 tv = tgt[bb * Nt + tb + tid];
        float a0 = 3.4e38f, a1 = 3.4e38f, a2v = 3.4e38f;
        int i0 = 0, i1 = 0, i2 = 0;
        for (int a = 0; a < n; ++a) {
            int j = scand[tid][a];
            float4 sv = src[bb * Ns + j];
            float dx = tv.x - sv.x, dy = tv.y - sv.y, dz = tv.z - sv.z;
            float d2 = __fadd_rn(__fadd_rn(__fmul_rn(dx, dx), __fmul_rn(dy, dy)),
                                 __fmul_rn(dz, dz));
            bool c0 = d2 < a0, c1 = d2 < a1, c2 = d2 < a2v;
            float n2v = fminf(a2v, fmaxf(a1, d2));
            float n1 = __builtin_amdgcn_fmed3f(a0, a1, d2);
            float n0 = fminf(a0, d2);
            i2 = c1 ? i1 : (c2 ? j : i2);
            i1 = c0 ? i0 : (c1 ? j : i1);
            i0 = c0 ? j : i0;
            a0 = n0; a1 = n1; a2v = n2v;
        }
        float d0 = sqrtf(fmaxf(a0, 0.f));
        float d1 = sqrtf(fmaxf(a1, 0.f));
        float d2s = sqrtf(fmaxf(a2v, 0.f));
        float w0 = 1.f / (d0 + 1e-8f);
        float w1 = 1.f / (d1 + 1e-8f);
        float w2 = 1.f / (d2s + 1e-8f);
        float wsum = w0 + w1 + w2;
        swv[tid][0] = w0 / wsum; swv[tid][1] = w1 / wsum; swv[tid][2] = w2 / wsum;
        sgv[tid][0] = i0; sgv[tid][1] = i1; sgv[tid][2] = i2;
    }
    __syncthreads();

    // ---- gather: 32 targets x 64 channel-pairs ----
    for (int e = tid; e < 32 * 64; e += 256) {
        int tt = e >> 6, cp = (e & 63) * 2;
        int base = bb * Ns * 128;
        float2 f0  = *(const float2*)&feats[base + sgv[tt][0] * 128 + cp];
        float2 f1  = *(const float2*)&feats[base + sgv[tt][1] * 128 + cp];
        float2 f2v = *(const float2*)&feats[base + sgv[tt][2] * 128 + cp];
        float2 o;
        o.x = swv[tt][0] * f0.x + swv[tt][1] * f1.x + swv[tt][2] * f2v.x;
        o.y = swv[tt][0] * f0.y + swv[tt][1] * f1.y + swv[tt][2] * f2v.y;
        *(float2*)&out[(bb * Nt + tb + tt) * 128 + cp] = o;
    }
}

// ---------- GEMM A (MFMA bf16, +fused BN stats): H = [L|R] @ W^T ---------- (R9-proven)
__global__ __launch_bounds__(256)
void gemm_a_kernel(const float* __restrict__ L, const float* __restrict__ R,
                   const float* __restrict__ W, float* __restrict__ H,
                   float* __restrict__ st) {
    __shared__ short Asm[4096];
    __shared__ short Bsm[2048];
    int tid = threadIdx.x;
    int lane = tid & 63, w = tid >> 6;
    int m16 = lane & 15, quad = lane >> 4;
    int rowBase = blockIdx.y * 128;
    int colBase = blockIdx.x * 64;
    f32x4 acc[2][4] = {};
    for (int k0 = 0; k0 < 256; k0 += 32) {
        #pragma unroll
        for (int i = 0; i < 2; ++i) {
            int u = tid + i * 256;
            int r = u >> 2, g = u & 3;
            const float* p = (k0 < 128) ? &L[(rowBase + r) * 128 + k0 + g * 8]
                                        : &R[(rowBase + r) * 128 + (k0 - 128) + g * 8];
            float4 x = *(const float4*)p, y = *(const float4*)(p + 4);
            uint4 pk = make_uint4(pack2(x.x, x.y), pack2(x.z, x.w),
                                  pack2(y.x, y.y), pack2(y.z, y.w));
            int blk = (r >> 4) * 64 + (r & 15) * 4 + g;
            *(uint4*)&Asm[blk * 8] = pk;
        }
        {
            int n = tid >> 2, g = tid & 3;
            const float* p = &W[(colBase + n) * 256 + k0 + g * 8];
            float4 x = *(const float4*)p, y = *(const float4*)(p + 4);
            uint4 pk = make_uint4(pack2(x.x, x.y), pack2(x.z, x.w),
                                  pack2(y.x, y.y), pack2(y.z, y.w));
            int blk = (n >> 4) * 64 + (n & 15) * 4 + g;
            *(uint4*)&Bsm[blk * 8] = pk;
        }
        __syncthreads();
        bf16x8 a0 = *(const bf16x8*)&Asm[((2 * w + 0) * 64 + m16 * 4 + quad) * 8];
        bf16x8 a1 = *(const bf16x8*)&Asm[((2 * w + 1) * 64 + m16 * 4 + quad) * 8];
        #pragma unroll
        for (int ct = 0; ct < 4; ++ct) {
            bf16x8 bf = *(const bf16x8*)&Bsm[(ct * 64 + m16 * 4 + quad) * 8];
            acc[0][ct] = __builtin_amdgcn_mfma_f32_16x16x32_bf16(a0, bf, acc[0][ct], 0, 0, 0);
            acc[1][ct] = __builtin_amdgcn_mfma_f32_16x16x32_bf16(a1, bf, acc[1][ct], 0, 0, 0);
        }
        __syncthreads();
    }
    #pragma unroll
    for (int rt = 0; rt < 2; ++rt)
        #pragma unroll
        for (int r = 0; r < 4; ++r) {
            int row = rowBase + (2 * w + rt) * 16 + quad * 4 + r;
            #pragma unroll
            for (int ct = 0; ct < 4; ++ct)
                H[row * 128 + colBase + ct * 16 + m16] = acc[rt][ct][r];
        }
    float* ssum = (float*)Asm;
    float* ssq  = (float*)Asm + 1024;
    #pragma unroll
    for (int ct = 0; ct < 4; ++ct) {
        float s = 0.f, q = 0.f;
        #pragma unroll
        for (int rt = 0; rt < 2; ++rt)
            #pragma unroll
            for (int r = 0; r < 4; ++r) {
                float v = acc[rt][ct][r];
                s += v; q += v * v;
            }
        ssum[(w * 4 + quad) * 64 + ct * 16 + m16] = s;
        ssq [(w * 4 + quad) * 64 + ct * 16 + m16] = q;
    }
    __syncthreads();
    if (tid < 64) {
        float s = 0.f, q = 0.f;
        #pragma unroll
        for (int i = 0; i < 16; ++i) { s += ssum[i * 64 + tid]; q += ssq[i * 64 + tid]; }
        atomicAdd(&st[colBase + tid], s);
        atomicAdd(&st[128 + colBase + tid], q);
    }
}

// ---------- GEMM B (MFMA bf16, finalize fused) ---------- (R12/R13-proven)
__global__ __launch_bounds__(256)
void gemm_b_kernel(const float* __restrict__ Hin, const float* __restrict__ st,
                   const float* __restrict__ gam, const float* __restrict__ bet,
                   float invN, const float* __restrict__ W,
                   const float* __restrict__ bias, float* __restrict__ out) {
    __shared__ short Asm[4096];
    __shared__ short Bsm[2048];
    __shared__ float ssc[128], ssf[128];
    int tid = threadIdx.x;
    if (tid < 128) {
        float mu = st[tid] * invN;
        float var = st[128 + tid] * invN - mu * mu;
        float rstd = rsqrtf(fmaxf(var, 0.f) + 1e-5f);
        float sc = rstd * gam[tid];
        ssc[tid] = sc;
        ssf[tid] = bet[tid] - mu * sc;
    }
    __syncthreads();
    int lane = tid & 63, w = tid >> 6;
    int m16 = lane & 15, quad = lane >> 4;
    int rowBase = blockIdx.y * 128;
    int colBase = blockIdx.x * 64;
    f32x4 acc[2][4] = {};
    for (int k0 = 0; k0 < 128; k0 += 32) {
        #pragma unroll
        for (int i = 0; i < 2; ++i) {
            int u = tid + i * 256;
            int r = u >> 2, g = u & 3;
            int c = k0 + g * 8;
            const float* p = &Hin[(rowBase + r) * 128 + c];
            float4 x = *(const float4*)p, y = *(const float4*)(p + 4);
            float h0 = fmaxf(x.x * ssc[c+0] + ssf[c+0], 0.f);
            float h1 = fmaxf(x.y * ssc[c+1] + ssf[c+1], 0.f);
            float h2 = fmaxf(x.z * ssc[c+2] + ssf[c+2], 0.f);
            float h3 = fmaxf(x.w * ssc[c+3] + ssf[c+3], 0.f);
            float h4 = fmaxf(y.x * ssc[c+4] + ssf[c+4], 0.f);
            float h5 = fmaxf(y.y * ssc[c+5] + ssf[c+5], 0.f);
            float h6 = fmaxf(y.z * ssc[c+6] + ssf[c+6], 0.f);
            float h7 = fmaxf(y.w * ssc[c+7] + ssf[c+7], 0.f);
            uint4 pk = make_uint4(pack2(h0, h1), pack2(h2, h3),
                                  pack2(h4, h5), pack2(h6, h7));
            int blk = (r >> 4) * 64 + (r & 15) * 4 + g;
            *(uint4*)&Asm[blk * 8] = pk;
        }
        {
            int n = tid >> 2, g = tid & 3;
            const float* p = &W[(colBase + n) * 128 + k0 + g * 8];
            float4 x = *(const float4*)p, y = *(const float4*)(p + 4);
            uint4 pk = make_uint4(pack2(x.x, x.y), pack2(x.z, x.w),
                                  pack2(y.x, y.y), pack2(y.z, y.w));
            int blk = (n >> 4) * 64 + (n & 15) * 4 + g;
            *(uint4*)&Bsm[blk * 8] = pk;
        }
        __syncthreads();
        bf16x8 a0 = *(const bf16x8*)&Asm[((2 * w + 0) * 64 + m16 * 4 + quad) * 8];
        bf16x8 a1 = *(const bf16x8*)&Asm[((2 * w + 1) * 64 + m16 * 4 + quad) * 8];
        #pragma unroll
        for (int ct = 0; ct < 4; ++ct) {
            bf16x8 bf = *(const bf16x8*)&Bsm[(ct * 64 + m16 * 4 + quad) * 8];
            acc[0][ct] = __builtin_amdgcn_mfma_f32_16x16x32_bf16(a0, bf, acc[0][ct], 0, 0, 0);
            acc[1][ct] = __builtin_amdgcn_mfma_f32_16x16x32_bf16(a1, bf, acc[1][ct], 0, 0, 0);
        }
        __syncthreads();
    }
    #pragma unroll
    for (int ct = 0; ct < 4; ++ct) {
        float bv = bias[colBase + ct * 16 + m16];
        #pragma unroll
        for (int rt = 0; rt < 2; ++rt)
            #pragma unroll
            for (int r = 0; r < 4; ++r) {
                int row = rowBase + (2 * w + rt) * 16 + quad * 4 + r;
                out[row * 128 + colBase + ct * 16 + m16] = acc[rt][ct][r] + bv;
            }
    }
}

extern "C" void kernel_launch(void* const* d_in, const int* in_sizes, int n_in,
                              void* d_out, int out_size, void* d_ws, size_t ws_size,
                              hipStream_t stream) {
    const float* pts_r1 = (const float*)d_in[0];   // (2,8192,3)
    const float* pts_r2 = (const float*)d_in[1];   // (2,4096,3)
    const float* pts_r4 = (const float*)d_in[2];   // (2,2048,3)
    const float* feat0  = (const float*)d_in[3];   // (16384,128)
    const float* feat1  = (const float*)d_in[4];   // (8192,128)
    const float* feat2  = (const float*)d_in[5];   // (4096,128)
    const float* w3a = (const float*)d_in[6];      // (128,256)
    const float* g3  = (const float*)d_in[7];
    const float* b3  = (const float*)d_in[8];
    const float* w3b = (const float*)d_in[9];      // (128,128)
    const float* bb3 = (const float*)d_in[10];
    const float* w4a = (const float*)d_in[11];     // (128,256)
    const float* g4  = (const float*)d_in[12];
    const float* b4  = (const float*)d_in[13];
    const float* w4b = (const float*)d_in[14];     // (128,128)
    const float* bb4 = (const float*)d_in[15];

    float* wsf = (float*)d_ws;
    float4* xyz1 = (float4*)(wsf + 0);        // 16384 pts
    float4* xyz2 = (float4*)(wsf + 65536);    // 8192 pts
    float4* xyz4 = (float4*)(wsf + 98304);    // 4096 pts
    float* f2i = wsf + 114688;                // 8192*128
    float* H1  = wsf + 1163264;               // 8192*128
    float* n3  = wsf + 2211840;               // 8192*128
    float* n3i = wsf + 114688;                // 16384*128 (over f2i+H1, both dead)
    float* H2  = wsf + 3260416;               // 16384*128
    float* st1 = wsf + 5357568;               // 256 (sum | sumsq)
    float* st2 = wsf + 5358080;               // 256
    // key fragments aliased into H2 (H2 written only by fnode-4 gemm_a,
    // after both interps have consumed the fragments)
    uint4* bf2lo = (uint4*)(wsf + 3260416);   // 8192 x 16B
    uint4* bf2hi = bf2lo + 8192;              // 8192 x 16B
    uint4* bf4lo = bf2hi + 8192;              // 4096 x 16B
    uint4* bf4hi = bf4lo + 4096;              // 4096 x 16B

    // 1. prep: pad xyz, build key fragments, zero stat accumulators
    prep_kernel<<<112, 256, 0, stream>>>(pts_r1, pts_r2, pts_r4, xyz1, xyz2, xyz4,
                                         bf2lo, bf2hi, bf4lo, bf4hi, st1, st2);
    // 2. interp #1: feat2 (pts_r4 grid, Ns=2048) -> pts_r2 targets (Nt=4096)
    nn_interp_mfma<<<dim3(128, 2), 256, 0, stream>>>(xyz2, 4096, xyz4, 2048,
                                                     bf4lo, bf4hi, feat2, f2i);
    // 3. fnode 3
    gemm_a_kernel<<<dim3(2, 64), 256, 0, stream>>>(feat1, f2i, w3a, H1, st1);
    gemm_b_kernel<<<dim3(2, 64), 256, 0, stream>>>(H1, st1, g3, b3, 1.f / 8192.f,
                                                   w3b, bb3, n3);
    // 4. interp #2: n3 (pts_r2 grid, Ns=4096) -> pts_r1 targets (Nt=8192)
    nn_interp_mfma<<<dim3(256, 2), 256, 0, stream>>>(xyz1, 8192, xyz2, 4096,
                                                     bf2lo, bf2hi, n3, n3i);
    // 5. fnode 4
    gemm_a_kernel<<<dim3(2, 128), 256, 0, stream>>>(feat0, n3i, w4a, H2, st2);
    gemm_b_kernel<<<dim3(2, 128), 256, 0, stream>>>(H2, st2, g4, b4, 1.f / 16384.f,
                                                    w4b, bb4, (float*)d_out);
}